// Round 3
// baseline (276.270 us; speedup 1.0000x reference)
//
#include <hip/hip_runtime.h>

#define N_USER 100000
#define N_ITEM 50000
#define E_R    500000
#define E_T    250000
#define NB     (1 << 20)       // histogram bins
#define NCH    4096            // chunks of 256 bins
#define ZMIN   (-4.0f)
#define ZSCALE ((float)NB / 8.0f)
#define NBLK_R 512             // rated-edge blocks
#define NBLK_T 512             // trust-edge blocks

__device__ __forceinline__ float sigmoidf(float z) {
  return 1.0f / (1.0f + expf(-z));
}

__device__ __forceinline__ float dot4(float4 a, float4 b) {
  return a.x * b.x + a.y * b.y + a.z * b.z + a.w * b.w;
}

__device__ __forceinline__ float wave_sum_f(float v) {
#pragma unroll
  for (int off = 32; off > 0; off >>= 1) v += __shfl_xor(v, off, 64);
  return v;
}

__device__ __forceinline__ double wave_sum_d(double v) {
#pragma unroll
  for (int off = 32; off > 0; off >>= 1) v += __shfl_xor(v, off, 64);
  return v;
}

// ---------------- K1: collapse the affine chains into per-feature vectors ---
// wts[0..256)   = W4@W5@W6 (slices: [0:64) item_int, [64:128) x_u,
//                 [128:192) x_i, [192:256) user_int)
// wts[256]      = b4@W5@W6 + b5@W6 + b6
// wts[320..448) = W_so@W_so2 ([320:384) t_src, [384:448) t_dst)
// wts[448]      = b_so@W_so2 + b_so2
__global__ void k_collapse(const float* __restrict__ W4w, const float* __restrict__ W4b,
                           const float* __restrict__ W5w, const float* __restrict__ W5b,
                           const float* __restrict__ W6w, const float* __restrict__ W6b,
                           const float* __restrict__ Wsow, const float* __restrict__ Wsob,
                           const float* __restrict__ Wso2w, const float* __restrict__ Wso2b,
                           float* __restrict__ wts) {
  __shared__ float v56[128];
  int t = threadIdx.x;
  if (t < 128) {
    float s = 0.f;
    for (int k = 0; k < 64; ++k) s += W5w[t * 64 + k] * W6w[k];
    v56[t] = s;
  }
  __syncthreads();
  {
    float s = 0.f;
    for (int j = 0; j < 128; ++j) s += W4w[t * 128 + j] * v56[j];
    wts[t] = s;
  }
  if (t < 128) {
    float s = 0.f;
    for (int k = 0; k < 64; ++k) s += Wsow[t * 64 + k] * Wso2w[k];
    wts[320 + t] = s;
  }
  // biases via wave 0
  if (t < 64) {
    float pb = W5b[t] * W6w[t] + W4b[t] * v56[t] + W4b[64 + t] * v56[64 + t];
    float ps = Wsob[t] * Wso2w[t];
    pb = wave_sum_f(pb);
    ps = wave_sum_f(ps);
    if (t == 0) {
      wts[256] = pb + W6b[0];
      wts[448] = ps + Wso2b[0];
    }
  }
}

// ---------------- K2: per-node scalars, float4 loads, 4 nodes per wave ------
// 16 lanes per node (q = dim quad, g = node-in-group); one 4-step butterfly
// reduces all 4 nodes of a sum at once. blocks [0,1024): users; rest: items.
__global__ void k_nodes(const float* __restrict__ xu, const float* __restrict__ ui,
                        const float* __restrict__ au, const float* __restrict__ tt,
                        const float* __restrict__ xi, const float* __restrict__ ii,
                        const float* __restrict__ ai,
                        const float* __restrict__ Wattw, const float* __restrict__ wts,
                        float2* __restrict__ u_rate, float2* __restrict__ u_trust,
                        float2* __restrict__ i_rate) {
  int lane = threadIdx.x & 63;
  int wib = threadIdx.x >> 6;
  int g = lane >> 4;   // node within 4-node tile
  int q = lane & 15;   // float4 index within node row
  if (blockIdx.x < 1024) {
    const float4* xu4 = (const float4*)xu;
    const float4* ui4 = (const float4*)ui;
    const float4* au4 = (const float4*)au;
    const float4* tt4 = (const float4*)tt;
    float4 wex = ((const float4*)(wts + 64))[q];
    float4 weu = ((const float4*)(wts + 192))[q];
    float4 wa  = ((const float4*)Wattw)[q];
    float4 w1  = ((const float4*)(wts + 320))[q];
    float4 w2  = ((const float4*)(wts + 384))[q];
    int wave = blockIdx.x * 4 + wib;
    const int nw = 4096;
    for (int tile = wave; tile < N_USER / 4; tile += nw) {
      int node = tile * 4 + g;
      int base = node * 16 + q;
      float4 x = xu4[base], uv = ui4[base], a = au4[base], tv = tt4[base];
      float s0 = dot4(x, wex) + dot4(uv, weu);
      float s1 = dot4(a, wa);
      float s2 = dot4(tv, w1);
      float s3 = dot4(tv, w2);
#pragma unroll
      for (int off = 1; off < 16; off <<= 1) {
        s0 += __shfl_xor(s0, off, 64);
        s1 += __shfl_xor(s1, off, 64);
        s2 += __shfl_xor(s2, off, 64);
        s3 += __shfl_xor(s3, off, 64);
      }
      if (q == 0) {
        u_rate[node]  = make_float2(s0, s1);
        u_trust[node] = make_float2(s2, s3);
      }
    }
  } else {
    const float4* xi4 = (const float4*)xi;
    const float4* ii4 = (const float4*)ii;
    const float4* ai4 = (const float4*)ai;
    float4 wei  = ((const float4*)(wts + 0))[q];
    float4 wexi = ((const float4*)(wts + 128))[q];
    float4 wai  = ((const float4*)(Wattw + 64))[q];
    int wave = (blockIdx.x - 1024) * 4 + wib;
    const int nw = 2048;
    for (int tile = wave; tile < N_ITEM / 4; tile += nw) {
      int node = tile * 4 + g;
      int base = node * 16 + q;
      float4 x = xi4[base], iv = ii4[base], a = ai4[base];
      float s0 = dot4(iv, wei) + dot4(x, wexi);
      float s1 = dot4(a, wai);
#pragma unroll
      for (int off = 1; off < 16; off <<= 1) {
        s0 += __shfl_xor(s0, off, 64);
        s1 += __shfl_xor(s1, off, 64);
      }
      if (q == 0) i_rate[node] = make_float2(s0, s1);
    }
  }
}

// ---------------- K3: edges, 4 per thread. [0,NBLK_R): rated; rest: trust ---
__global__ void k_edges(const int* __restrict__ src, const int* __restrict__ dst,
                        const float* __restrict__ boun3,
                        const float2* __restrict__ u_rate, const float2* __restrict__ i_rate,
                        const int* __restrict__ tps, const int* __restrict__ tpd,
                        const int* __restrict__ tns, const int* __restrict__ tnd,
                        const float2* __restrict__ u_trust,
                        const float* __restrict__ wts, const float* __restrict__ Wattb,
                        float* __restrict__ out,
                        unsigned* __restrict__ histP, unsigned* __restrict__ histN,
                        double* __restrict__ partR, double* __restrict__ partT) {
  __shared__ double sd[4];
  float local = 0.f;
  if (blockIdx.x < NBLK_R) {
    float batt = Wattb[0];
    float beff = wts[256];
    const int4* src4 = (const int4*)src;
    const int4* dst4 = (const int4*)dst;
    const float4* b4 = (const float4*)boun3;
    float4* out4 = (float4*)out;
    for (int e = blockIdx.x * 256 + threadIdx.x; e < E_R / 4; e += NBLK_R * 256) {
      int4 s = src4[e], d = dst4[e];
      float4 bo = b4[e];
      float2 ur0 = u_rate[s.x], ur1 = u_rate[s.y], ur2 = u_rate[s.z], ur3 = u_rate[s.w];
      float2 ir0 = i_rate[d.x], ir1 = i_rate[d.y], ir2 = i_rate[d.z], ir3 = i_rate[d.w];
      out4[e] = make_float4(ur0.x + ir0.x + beff, ur1.x + ir1.x + beff,
                            ur2.x + ir2.x + beff, ur3.x + ir3.x + beff);
      float d0 = bo.x - sigmoidf(ur0.y + ir0.y + batt) + 1e-10f;
      float d1 = bo.y - sigmoidf(ur1.y + ir1.y + batt) + 1e-10f;
      float d2 = bo.z - sigmoidf(ur2.y + ir2.y + batt) + 1e-10f;
      float d3 = bo.w - sigmoidf(ur3.y + ir3.y + batt) + 1e-10f;
      local += d0 * d0 + d1 * d1 + d2 * d2 + d3 * d3;
    }
    float w = wave_sum_f(local);
    if ((threadIdx.x & 63) == 0) sd[threadIdx.x >> 6] = (double)w;
    __syncthreads();
    if (threadIdx.x == 0) partR[blockIdx.x] = sd[0] + sd[1] + sd[2] + sd[3];
  } else {
    float bso = wts[448];
    int b = blockIdx.x - NBLK_R;
    const int4* tps4 = (const int4*)tps;
    const int4* tpd4 = (const int4*)tpd;
    const int4* tns4 = (const int4*)tns;
    const int4* tnd4 = (const int4*)tnd;
    for (int e = b * 256 + threadIdx.x; e < 2 * E_T / 4; e += NBLK_T * 256) {
      int4 s, d;
      int lab;
      if (e < E_T / 4) { s = tps4[e]; d = tpd4[e]; lab = 1; }
      else             { s = tns4[e - E_T / 4]; d = tnd4[e - E_T / 4]; lab = 0; }
      unsigned* hist = lab ? histP : histN;
      float z0 = u_trust[s.x].x + u_trust[d.x].y + bso;
      float z1 = u_trust[s.y].x + u_trust[d.y].y + bso;
      float z2 = u_trust[s.z].x + u_trust[d.z].y + bso;
      float z3 = u_trust[s.w].x + u_trust[d.w].y + bso;
      float base = lab ? 1.0f : 0.0f;
      float d0 = base - sigmoidf(z0) + 1e-10f;
      float d1 = base - sigmoidf(z1) + 1e-10f;
      float d2 = base - sigmoidf(z2) + 1e-10f;
      float d3 = base - sigmoidf(z3) + 1e-10f;
      local += d0 * d0 + d1 * d1 + d2 * d2 + d3 * d3;
      int b0 = (int)((z0 - ZMIN) * ZSCALE); b0 = b0 < 0 ? 0 : (b0 >= NB ? NB - 1 : b0);
      int b1 = (int)((z1 - ZMIN) * ZSCALE); b1 = b1 < 0 ? 0 : (b1 >= NB ? NB - 1 : b1);
      int b2 = (int)((z2 - ZMIN) * ZSCALE); b2 = b2 < 0 ? 0 : (b2 >= NB ? NB - 1 : b2);
      int b3 = (int)((z3 - ZMIN) * ZSCALE); b3 = b3 < 0 ? 0 : (b3 >= NB ? NB - 1 : b3);
      atomicAdd(&hist[b0], 1u);
      atomicAdd(&hist[b1], 1u);
      atomicAdd(&hist[b2], 1u);
      atomicAdd(&hist[b3], 1u);
    }
    float w = wave_sum_f(local);
    if ((threadIdx.x & 63) == 0) sd[threadIdx.x >> 6] = (double)w;
    __syncthreads();
    if (threadIdx.x == 0) partT[b] = sd[0] + sd[1] + sd[2] + sd[3];
  }
}

// ---------------- K4: per-chunk (256-bin) sums, wave per chunk --------------
__global__ void k_chunksum(const uint4* __restrict__ hP4, const uint4* __restrict__ hN4,
                           unsigned* __restrict__ chP, unsigned* __restrict__ chN) {
  int t = threadIdx.x, lane = t & 63, w = t >> 6;
  int chunk = blockIdx.x * 4 + w;
  int idx = chunk * 64 + lane;
  uint4 p = hP4[idx], n = hN4[idx];
  unsigned sp = p.x + p.y + p.z + p.w;
  unsigned sn = n.x + n.y + n.z + n.w;
#pragma unroll
  for (int off = 32; off > 0; off >>= 1) {
    sp += __shfl_xor(sp, off, 64);
    sn += __shfl_xor(sn, off, 64);
  }
  if (lane == 0) { chP[chunk] = sp; chN[chunk] = sn; }
}

// ---------------- K5: exclusive scan over the 4096 chunk sums ---------------
__global__ void k_scan(const unsigned* __restrict__ chP, const unsigned* __restrict__ chN,
                       unsigned* __restrict__ prefP, unsigned* __restrict__ prefN) {
  __shared__ unsigned shp[1024], shn[1024];
  int t = threadIdx.x;
  int base = t * 4;
  unsigned ep[4], en[4], runp = 0, runn = 0;
#pragma unroll
  for (int i = 0; i < 4; ++i) {
    ep[i] = runp; en[i] = runn;
    runp += chP[base + i]; runn += chN[base + i];
  }
  shp[t] = runp; shn[t] = runn;
  __syncthreads();
  for (int off = 1; off < 1024; off <<= 1) {
    unsigned ap_ = 0, an_ = 0;
    if (t >= off) { ap_ = shp[t - off]; an_ = shn[t - off]; }
    __syncthreads();
    shp[t] += ap_; shn[t] += an_;
    __syncthreads();
  }
  unsigned exP = shp[t] - runp, exN = shn[t] - runn;
#pragma unroll
  for (int i = 0; i < 4; ++i) {
    prefP[base + i] = exP + ep[i];
    prefN[base + i] = exN + en[i];
  }
}

// ---------------- K6: per-bin AUC / AP contributions → per-block partials ---
__global__ void k_aucap(const unsigned* __restrict__ histP, const unsigned* __restrict__ histN,
                        const unsigned* __restrict__ prefP, const unsigned* __restrict__ prefN,
                        double* __restrict__ partC, double* __restrict__ partA) {
  __shared__ unsigned sp[256], sn[256];
  int t = threadIdx.x;
  int bin = blockIdx.x * 256 + t;
  unsigned np = histP[bin], nn = histN[bin];
  sp[t] = np; sn[t] = nn;
  __syncthreads();
  for (int off = 1; off < 256; off <<= 1) {
    unsigned ap_ = 0, an_ = 0;
    if (t >= off) { ap_ = sp[t - off]; an_ = sn[t - off]; }
    __syncthreads();
    sp[t] += ap_; sn[t] += an_;
    __syncthreads();
  }
  unsigned PA = prefP[blockIdx.x] + sp[t] - np;  // #pos in strictly lower bins
  unsigned NA = prefN[blockIdx.x] + sn[t] - nn;  // #neg in strictly lower bins
  double Cc = (double)np * (double)NA + 0.5 * (double)np * (double)nn;
  double apc = 0.0;
  if (np > 0) {
    double cpa = (double)(E_T - PA - np);  // pos strictly higher (earlier desc)
    double cna = (double)(E_T - NA - nn);
    double ratio = (double)(np + nn) / (double)np;
    for (unsigned j = 1; j <= np; ++j) {
      double r = ((double)j - 0.5) * ratio + 0.5;  // modeled local rank
      apc += (cpa + (double)j) / (cpa + cna + r);
    }
  }
  double c = wave_sum_d(Cc);
  double a = wave_sum_d(apc);
  __shared__ double dc[4], da[4];
  int lane = t & 63, w = t >> 6;
  if (lane == 0) { dc[w] = c; da[w] = a; }
  __syncthreads();
  if (t == 0) {
    partC[blockIdx.x] = dc[0] + dc[1] + dc[2] + dc[3];
    partA[blockIdx.x] = da[0] + da[1] + da[2] + da[3];
  }
}

// ---------------- K7: final reduce + scalar outputs -------------------------
__global__ void k_final(const double* __restrict__ partR, const double* __restrict__ partT,
                        const double* __restrict__ partC, const double* __restrict__ partA,
                        float* __restrict__ out) {
  int t = threadIdx.x;
  double sR = 0, sT = 0, sC = 0, sA = 0;
  for (int i = t; i < NBLK_R; i += 256) sR += partR[i];
  for (int i = t; i < NBLK_T; i += 256) sT += partT[i];
  for (int i = t; i < 4096; i += 256) { sC += partC[i]; sA += partA[i]; }
  sR = wave_sum_d(sR); sT = wave_sum_d(sT);
  sC = wave_sum_d(sC); sA = wave_sum_d(sA);
  __shared__ double sh[4][4];
  int lane = t & 63, w = t >> 6;
  if (lane == 0) { sh[w][0] = sR; sh[w][1] = sT; sh[w][2] = sC; sh[w][3] = sA; }
  __syncthreads();
  if (t == 0) {
    double R = sh[0][0] + sh[1][0] + sh[2][0] + sh[3][0];
    double T = sh[0][1] + sh[1][1] + sh[2][1] + sh[3][1];
    double C = sh[0][2] + sh[1][2] + sh[2][2] + sh[3][2];
    double A = sh[0][3] + sh[1][3] + sh[2][3] + sh[3][3];
    out[E_R + 0] = (float)sqrt(R / (double)E_R);              // l_att
    out[E_R + 1] = (float)(C / ((double)E_T * (double)E_T));  // auc
    out[E_R + 2] = (float)(A / (double)E_T);                  // ap
    out[E_R + 3] = (float)sqrt(T / (double)(2 * E_T));        // loss_trust
  }
}

extern "C" void kernel_launch(void* const* d_in, const int* in_sizes, int n_in,
                              void* d_out, int out_size, void* d_ws, size_t ws_size,
                              hipStream_t stream) {
  (void)in_sizes; (void)n_in; (void)out_size; (void)ws_size;
  const float* x_u        = (const float*)d_in[0];
  const float* x_i        = (const float*)d_in[1];
  const float* a_u        = (const float*)d_in[2];
  const float* a_i        = (const float*)d_in[3];
  const float* t          = (const float*)d_in[4];
  const float* boun3      = (const float*)d_in[5];
  const float* user_int   = (const float*)d_in[6];
  const float* item_int   = (const float*)d_in[7];
  const float* W_att_w    = (const float*)d_in[8];
  const float* W_att_b    = (const float*)d_in[9];
  const float* W4_w       = (const float*)d_in[10];
  const float* W4_b       = (const float*)d_in[11];
  const float* W5_w       = (const float*)d_in[12];
  const float* W5_b       = (const float*)d_in[13];
  const float* W6_w       = (const float*)d_in[14];
  const float* W6_b       = (const float*)d_in[15];
  const float* W_so_w     = (const float*)d_in[16];
  const float* W_so_b     = (const float*)d_in[17];
  const float* W_so2_w    = (const float*)d_in[18];
  const float* W_so2_b    = (const float*)d_in[19];
  const int*   rated_src  = (const int*)d_in[20];
  const int*   rated_dst  = (const int*)d_in[21];
  const int*   tp_src     = (const int*)d_in[22];
  const int*   tp_dst     = (const int*)d_in[23];
  const int*   tn_src     = (const int*)d_in[24];
  const int*   tn_dst     = (const int*)d_in[25];
  float* out = (float*)d_out;

  // workspace layout (doubles first; everything written every call)
  char* ws = (char*)d_ws;
  double* partR   = (double*)ws;                        // NBLK_R
  double* partT   = partR + NBLK_R;                     // NBLK_T
  double* partC   = partT + NBLK_T;                     // 4096
  double* partA   = partC + 4096;                       // 4096
  unsigned* histP = (unsigned*)(partA + 4096);          // 4 MB
  unsigned* histN = histP + NB;                         // 4 MB
  unsigned* chP   = histN + NB;                         // 16 KB each
  unsigned* chN   = chP + NCH;
  unsigned* prefP = chN + NCH;
  unsigned* prefN = prefP + NCH;
  float* wts      = (float*)(prefN + NCH);              // 512 floats reserved
  float2* u_rate  = (float2*)(wts + 512);               // {s_user, att_u}
  float2* u_trust = u_rate + N_USER;                    // {ts_src, ts_dst}
  float2* i_rate  = u_trust + N_USER;                   // {s_item, att_i}

  hipMemsetAsync(histP, 0, (size_t)2 * NB * sizeof(unsigned), stream);

  k_collapse<<<1, 256, 0, stream>>>(W4_w, W4_b, W5_w, W5_b, W6_w, W6_b,
                                    W_so_w, W_so_b, W_so2_w, W_so2_b, wts);
  k_nodes<<<1536, 256, 0, stream>>>(x_u, user_int, a_u, t, x_i, item_int, a_i,
                                    W_att_w, wts, u_rate, u_trust, i_rate);
  k_edges<<<NBLK_R + NBLK_T, 256, 0, stream>>>(rated_src, rated_dst, boun3, u_rate, i_rate,
                                    tp_src, tp_dst, tn_src, tn_dst, u_trust,
                                    wts, W_att_b, out, histP, histN, partR, partT);
  k_chunksum<<<1024, 256, 0, stream>>>((const uint4*)histP, (const uint4*)histN, chP, chN);
  k_scan<<<1, 1024, 0, stream>>>(chP, chN, prefP, prefN);
  k_aucap<<<NCH, 256, 0, stream>>>(histP, histN, prefP, prefN, partC, partA);
  k_final<<<1, 256, 0, stream>>>(partR, partT, partC, partA, out);
}

// Round 5
// 264.567 us; speedup vs baseline: 1.0442x; 1.0442x over previous
//
#include <hip/hip_runtime.h>

#define N_USER 100000
#define N_ITEM 50000
#define E_R    500000
#define E_T    250000
#define NB     (1 << 20)       // histogram bins
#define NCH    4096            // chunks of 256 bins
#define ZMIN   (-4.0f)
#define ZSCALE ((float)NB / 8.0f)
#define UW     12500           // user waves (8 nodes each)
#define IW     6250            // item waves (8 nodes each)
#define TW     (UW + IW)       // 18750 one-shot waves
#define NODE_BLOCKS ((TW + 3) / 4)   // 4688

__device__ __forceinline__ float sigmoidf(float z) {
  return 1.0f / (1.0f + expf(-z));
}

__device__ __forceinline__ float dot4(float4 a, float4 b) {
  return a.x * b.x + a.y * b.y + a.z * b.z + a.w * b.w;
}

__device__ __forceinline__ float wave_sum_f(float v) {
#pragma unroll
  for (int off = 32; off > 0; off >>= 1) v += __shfl_xor(v, off, 64);
  return v;
}

__device__ __forceinline__ unsigned wave_sum_u(unsigned v) {
#pragma unroll
  for (int off = 32; off > 0; off >>= 1) v += __shfl_xor(v, off, 64);
  return v;
}

__device__ __forceinline__ double wave_sum_d(double v) {
#pragma unroll
  for (int off = 32; off > 0; off >>= 1) v += __shfl_xor(v, off, 64);
  return v;
}

// ---------------- K1: collapse the affine chains into per-feature vectors ---
// wts[0..256)   = W4@W5@W6 (slices: [0:64) item_int, [64:128) x_u,
//                 [128:192) x_i, [192:256) user_int)
// wts[256]      = b4@W5@W6 + b5@W6 + b6
// wts[320..448) = W_so@W_so2 ([320:384) t_src, [384:448) t_dst)
// wts[448]      = b_so@W_so2 + b_so2
__global__ void k_collapse(const float* __restrict__ W4w, const float* __restrict__ W4b,
                           const float* __restrict__ W5w, const float* __restrict__ W5b,
                           const float* __restrict__ W6w, const float* __restrict__ W6b,
                           const float* __restrict__ Wsow, const float* __restrict__ Wsob,
                           const float* __restrict__ Wso2w, const float* __restrict__ Wso2b,
                           float* __restrict__ wts) {
  __shared__ float v56[128];
  int t = threadIdx.x;
  if (t < 128) {
    float s = 0.f;
    for (int k = 0; k < 64; ++k) s += W5w[t * 64 + k] * W6w[k];
    v56[t] = s;
  }
  __syncthreads();
  {
    float s = 0.f;
    for (int j = 0; j < 128; ++j) s += W4w[t * 128 + j] * v56[j];
    wts[t] = s;
  }
  if (t < 128) {
    float s = 0.f;
    for (int k = 0; k < 64; ++k) s += Wsow[t * 64 + k] * Wso2w[k];
    wts[320 + t] = s;
  }
  if (t < 64) {
    float pb = W5b[t] * W6w[t] + W4b[t] * v56[t] + W4b[64 + t] * v56[64 + t];
    float ps = Wsob[t] * Wso2w[t];
    pb = wave_sum_f(pb);
    ps = wave_sum_f(ps);
    if (t == 0) {
      wts[256] = pb + W6b[0];
      wts[448] = ps + Wso2b[0];
    }
  }
}

// ---------------- K2: per-node scalars, one-shot waves, 8 nodes per wave ----
// Also zeroes the 8 MB histogram (consumed later by k_edges).
__global__ void k_nodes(const float* __restrict__ xu, const float* __restrict__ ui,
                        const float* __restrict__ au, const float* __restrict__ tt,
                        const float* __restrict__ xi, const float* __restrict__ ii,
                        const float* __restrict__ ai,
                        const float* __restrict__ Wattw, const float* __restrict__ wts,
                        float2* __restrict__ u_rate, float2* __restrict__ u_trust,
                        float2* __restrict__ i_rate,
                        uint2* __restrict__ hz) {
  // zero histograms: 2*NB u32 = NB uint2 pairs laid out contiguously
  int idx = blockIdx.x * 256 + threadIdx.x;
  if (idx < NB) hz[idx] = make_uint2(0u, 0u);

  int lane = threadIdx.x & 63;
  int wave = blockIdx.x * 4 + (threadIdx.x >> 6);
  if (wave >= TW) return;
  int g = lane >> 4;   // node within float4-tile
  int q = lane & 15;   // float4 index within node row

  if (wave < UW) {
    const float4* xu4 = (const float4*)xu;
    const float4* ui4 = (const float4*)ui;
    const float4* au4 = (const float4*)au;
    const float4* tt4 = (const float4*)tt;
    int nA = wave * 8 + g;          // tile A node; tile B = nA + 4
    int baseA = nA * 16 + q;
    int baseB = baseA + 64;
    // 8 independent loads, all issued before first use
    float4 xA = xu4[baseA], xB = xu4[baseB];
    float4 uA = ui4[baseA], uB = ui4[baseB];
    float4 aA = au4[baseA], aB = au4[baseB];
    float4 tA = tt4[baseA], tB = tt4[baseB];
    float4 wex = ((const float4*)(wts + 64))[q];
    float4 weu = ((const float4*)(wts + 192))[q];
    float4 wa  = ((const float4*)Wattw)[q];
    float4 w1  = ((const float4*)(wts + 320))[q];
    float4 w2  = ((const float4*)(wts + 384))[q];
    float sA0 = dot4(xA, wex) + dot4(uA, weu);
    float sB0 = dot4(xB, wex) + dot4(uB, weu);
    float sA1 = dot4(aA, wa), sB1 = dot4(aB, wa);
    float sA2 = dot4(tA, w1), sB2 = dot4(tB, w1);
    float sA3 = dot4(tA, w2), sB3 = dot4(tB, w2);
#pragma unroll
    for (int off = 1; off < 16; off <<= 1) {
      sA0 += __shfl_xor(sA0, off, 64); sB0 += __shfl_xor(sB0, off, 64);
      sA1 += __shfl_xor(sA1, off, 64); sB1 += __shfl_xor(sB1, off, 64);
      sA2 += __shfl_xor(sA2, off, 64); sB2 += __shfl_xor(sB2, off, 64);
      sA3 += __shfl_xor(sA3, off, 64); sB3 += __shfl_xor(sB3, off, 64);
    }
    if (q == 0) {
      u_rate[nA]      = make_float2(sA0, sA1);
      u_trust[nA]     = make_float2(sA2, sA3);
      u_rate[nA + 4]  = make_float2(sB0, sB1);
      u_trust[nA + 4] = make_float2(sB2, sB3);
    }
  } else {
    const float4* xi4 = (const float4*)xi;
    const float4* ii4 = (const float4*)ii;
    const float4* ai4 = (const float4*)ai;
    int nA = (wave - UW) * 8 + g;
    int baseA = nA * 16 + q;
    int baseB = baseA + 64;
    float4 xA = xi4[baseA], xB = xi4[baseB];
    float4 iA = ii4[baseA], iB = ii4[baseB];
    float4 aA = ai4[baseA], aB = ai4[baseB];
    float4 wei  = ((const float4*)(wts + 0))[q];
    float4 wexi = ((const float4*)(wts + 128))[q];
    float4 wai  = ((const float4*)(Wattw + 64))[q];
    float sA0 = dot4(iA, wei) + dot4(xA, wexi);
    float sB0 = dot4(iB, wei) + dot4(xB, wexi);
    float sA1 = dot4(aA, wai), sB1 = dot4(aB, wai);
#pragma unroll
    for (int off = 1; off < 16; off <<= 1) {
      sA0 += __shfl_xor(sA0, off, 64); sB0 += __shfl_xor(sB0, off, 64);
      sA1 += __shfl_xor(sA1, off, 64); sB1 += __shfl_xor(sB1, off, 64);
    }
    if (q == 0) {
      i_rate[nA]     = make_float2(sA0, sA1);
      i_rate[nA + 4] = make_float2(sB0, sB1);
    }
  }
}

// ---------------- K3: edges, 2 per thread, one-shot. [0,1024): rated --------
__global__ void k_edges(const int* __restrict__ src, const int* __restrict__ dst,
                        const float* __restrict__ boun3,
                        const float2* __restrict__ u_rate, const float2* __restrict__ i_rate,
                        const int* __restrict__ tps, const int* __restrict__ tpd,
                        const int* __restrict__ tns, const int* __restrict__ tnd,
                        const float2* __restrict__ u_trust,
                        const float* __restrict__ wts, const float* __restrict__ Wattb,
                        float* __restrict__ out,
                        unsigned* __restrict__ histP, unsigned* __restrict__ histN,
                        double* __restrict__ partR, double* __restrict__ partT) {
  __shared__ double sd[4];
  float local = 0.f;
  if (blockIdx.x < 1024) {
    int e = blockIdx.x * 256 + threadIdx.x;   // pair of edges
    if (e < E_R / 2) {
      float batt = Wattb[0];
      float beff = wts[256];
      int2 s = ((const int2*)src)[e], d = ((const int2*)dst)[e];
      float2 bo = ((const float2*)boun3)[e];
      float2 ur0 = u_rate[s.x], ur1 = u_rate[s.y];
      float2 ir0 = i_rate[d.x], ir1 = i_rate[d.y];
      ((float2*)out)[e] = make_float2(ur0.x + ir0.x + beff, ur1.x + ir1.x + beff);
      float d0 = bo.x - sigmoidf(ur0.y + ir0.y + batt) + 1e-10f;
      float d1 = bo.y - sigmoidf(ur1.y + ir1.y + batt) + 1e-10f;
      local = d0 * d0 + d1 * d1;
    }
    float w = wave_sum_f(local);
    if ((threadIdx.x & 63) == 0) sd[threadIdx.x >> 6] = (double)w;
    __syncthreads();
    if (threadIdx.x == 0) partR[blockIdx.x] = sd[0] + sd[1] + sd[2] + sd[3];
  } else {
    int b = blockIdx.x - 1024;
    int e = b * 256 + threadIdx.x;            // pair within [pos|neg] stream
    if (e < E_T) {                            // E_T pairs = 2*E_T edges
      float bso = wts[448];
      int2 s, d;
      int lab;
      if (e < E_T / 2) { s = ((const int2*)tps)[e]; d = ((const int2*)tpd)[e]; lab = 1; }
      else { s = ((const int2*)tns)[e - E_T / 2]; d = ((const int2*)tnd)[e - E_T / 2]; lab = 0; }
      unsigned* hist = lab ? histP : histN;
      float z0 = u_trust[s.x].x + u_trust[d.x].y + bso;
      float z1 = u_trust[s.y].x + u_trust[d.y].y + bso;
      float base = lab ? 1.0f : 0.0f;
      float d0 = base - sigmoidf(z0) + 1e-10f;
      float d1 = base - sigmoidf(z1) + 1e-10f;
      local = d0 * d0 + d1 * d1;
      int b0 = (int)((z0 - ZMIN) * ZSCALE); b0 = b0 < 0 ? 0 : (b0 >= NB ? NB - 1 : b0);
      int b1 = (int)((z1 - ZMIN) * ZSCALE); b1 = b1 < 0 ? 0 : (b1 >= NB ? NB - 1 : b1);
      atomicAdd(&hist[b0], 1u);
      atomicAdd(&hist[b1], 1u);
    }
    float w = wave_sum_f(local);
    if ((threadIdx.x & 63) == 0) sd[threadIdx.x >> 6] = (double)w;
    __syncthreads();
    if (threadIdx.x == 0) partT[b] = sd[0] + sd[1] + sd[2] + sd[3];
  }
}

// ---------------- K4: per-chunk (256-bin) sums, wave per chunk --------------
__global__ void k_chunksum(const uint4* __restrict__ hP4, const uint4* __restrict__ hN4,
                           unsigned* __restrict__ chP, unsigned* __restrict__ chN) {
  int t = threadIdx.x, lane = t & 63, w = t >> 6;
  int chunk = blockIdx.x * 4 + w;
  int idx = chunk * 64 + lane;
  uint4 p = hP4[idx], n = hN4[idx];
  unsigned sp = p.x + p.y + p.z + p.w;
  unsigned sn = n.x + n.y + n.z + n.w;
  sp = wave_sum_u(sp);
  sn = wave_sum_u(sn);
  if (lane == 0) { chP[chunk] = sp; chN[chunk] = sn; }
}

// ---------------- K5: per-bin AUC / AP (chunk prefix computed in-block) -----
__global__ void k_aucap(const unsigned* __restrict__ histP, const unsigned* __restrict__ histN,
                        const unsigned* __restrict__ chP, const unsigned* __restrict__ chN,
                        double* __restrict__ partC, double* __restrict__ partA) {
  int t = threadIdx.x, lane = t & 63, w = t >> 6;
  int blk = blockIdx.x;
  // base = sum of chunk sums for chunks < blk
  unsigned bp = 0, bn = 0;
  for (int c = t; c < blk; c += 256) { bp += chP[c]; bn += chN[c]; }
  bp = wave_sum_u(bp);
  bn = wave_sum_u(bn);
  __shared__ unsigned sbp[4], sbn[4], swp[4], swn[4];
  if (lane == 0) { sbp[w] = bp; sbn[w] = bn; }
  // load bins + wave-level inclusive scan (Kogge-Stone)
  int bin = blk * 256 + t;
  unsigned np = histP[bin], nn = histN[bin];
  unsigned ip = np, in_ = nn;
#pragma unroll
  for (int off = 1; off < 64; off <<= 1) {
    int sl = lane >= off ? lane - off : lane;
    unsigned tp = __shfl(ip, sl, 64);
    unsigned tn = __shfl(in_, sl, 64);
    if (lane >= off) { ip += tp; in_ += tn; }
  }
  if (lane == 63) { swp[w] = ip; swn[w] = in_; }
  __syncthreads();
  unsigned base_p = sbp[0] + sbp[1] + sbp[2] + sbp[3];
  unsigned base_n = sbn[0] + sbn[1] + sbn[2] + sbn[3];
  unsigned wo_p = 0, wo_n = 0;
  for (int i = 0; i < 4; ++i) {
    if (i < w) { wo_p += swp[i]; wo_n += swn[i]; }
  }
  unsigned PA = base_p + wo_p + ip - np;  // #pos in strictly lower bins
  unsigned NA = base_n + wo_n + in_ - nn; // #neg in strictly lower bins
  double Cc = (double)np * (double)NA + 0.5 * (double)np * (double)nn;
  double apc = 0.0;
  if (np > 0) {
    double cpa = (double)(E_T - PA - np);  // pos strictly higher (earlier desc)
    double cna = (double)(E_T - NA - nn);
    double ratio = (double)(np + nn) / (double)np;
    for (unsigned j = 1; j <= np; ++j) {
      double r = ((double)j - 0.5) * ratio + 0.5;  // modeled local rank
      apc += (cpa + (double)j) / (cpa + cna + r);
    }
  }
  double c = wave_sum_d(Cc);
  double a = wave_sum_d(apc);
  __shared__ double dc[4], da[4];
  if (lane == 0) { dc[w] = c; da[w] = a; }
  __syncthreads();
  if (t == 0) {
    partC[blk] = dc[0] + dc[1] + dc[2] + dc[3];
    partA[blk] = da[0] + da[1] + da[2] + da[3];
  }
}

// ---------------- K6: final reduce + scalar outputs -------------------------
__global__ void k_final(const double* __restrict__ partR, const double* __restrict__ partT,
                        const double* __restrict__ partC, const double* __restrict__ partA,
                        float* __restrict__ out) {
  int t = threadIdx.x;
  double sR = 0, sT = 0, sC = 0, sA = 0;
  for (int i = t; i < 1024; i += 256) { sR += partR[i]; sT += partT[i]; }
  for (int i = t; i < 4096; i += 256) { sC += partC[i]; sA += partA[i]; }
  sR = wave_sum_d(sR); sT = wave_sum_d(sT);
  sC = wave_sum_d(sC); sA = wave_sum_d(sA);
  __shared__ double sh[4][4];
  int lane = t & 63, w = t >> 6;
  if (lane == 0) { sh[w][0] = sR; sh[w][1] = sT; sh[w][2] = sC; sh[w][3] = sA; }
  __syncthreads();
  if (t == 0) {
    double R = sh[0][0] + sh[1][0] + sh[2][0] + sh[3][0];
    double T = sh[0][1] + sh[1][1] + sh[2][1] + sh[3][1];
    double C = sh[0][2] + sh[1][2] + sh[2][2] + sh[3][2];
    double A = sh[0][3] + sh[1][3] + sh[2][3] + sh[3][3];
    out[E_R + 0] = (float)sqrt(R / (double)E_R);              // l_att
    out[E_R + 1] = (float)(C / ((double)E_T * (double)E_T));  // auc
    out[E_R + 2] = (float)(A / (double)E_T);                  // ap
    out[E_R + 3] = (float)sqrt(T / (double)(2 * E_T));        // loss_trust
  }
}

extern "C" void kernel_launch(void* const* d_in, const int* in_sizes, int n_in,
                              void* d_out, int out_size, void* d_ws, size_t ws_size,
                              hipStream_t stream) {
  (void)in_sizes; (void)n_in; (void)out_size; (void)ws_size;
  const float* x_u        = (const float*)d_in[0];
  const float* x_i        = (const float*)d_in[1];
  const float* a_u        = (const float*)d_in[2];
  const float* a_i        = (const float*)d_in[3];
  const float* t          = (const float*)d_in[4];
  const float* boun3      = (const float*)d_in[5];
  const float* user_int   = (const float*)d_in[6];
  const float* item_int   = (const float*)d_in[7];
  const float* W_att_w    = (const float*)d_in[8];
  const float* W_att_b    = (const float*)d_in[9];
  const float* W4_w       = (const float*)d_in[10];
  const float* W4_b       = (const float*)d_in[11];
  const float* W5_w       = (const float*)d_in[12];
  const float* W5_b       = (const float*)d_in[13];
  const float* W6_w       = (const float*)d_in[14];
  const float* W6_b       = (const float*)d_in[15];
  const float* W_so_w     = (const float*)d_in[16];
  const float* W_so_b     = (const float*)d_in[17];
  const float* W_so2_w    = (const float*)d_in[18];
  const float* W_so2_b    = (const float*)d_in[19];
  const int*   rated_src  = (const int*)d_in[20];
  const int*   rated_dst  = (const int*)d_in[21];
  const int*   tp_src     = (const int*)d_in[22];
  const int*   tp_dst     = (const int*)d_in[23];
  const int*   tn_src     = (const int*)d_in[24];
  const int*   tn_dst     = (const int*)d_in[25];
  float* out = (float*)d_out;

  // workspace layout (doubles first; everything written every call)
  char* ws = (char*)d_ws;
  double* partR   = (double*)ws;                        // 1024
  double* partT   = partR + 1024;                       // 1024
  double* partC   = partT + 1024;                       // 4096
  double* partA   = partC + 4096;                       // 4096
  unsigned* histP = (unsigned*)(partA + 4096);          // 4 MB
  unsigned* histN = histP + NB;                         // 4 MB (contiguous with histP)
  unsigned* chP   = histN + NB;                         // 16 KB each
  unsigned* chN   = chP + NCH;
  float* wts      = (float*)(chN + NCH);                // 512 floats reserved
  float2* u_rate  = (float2*)(wts + 512);               // {s_user, att_u}
  float2* u_trust = u_rate + N_USER;                    // {ts_src, ts_dst}
  float2* i_rate  = u_trust + N_USER;                   // {s_item, att_i}

  k_collapse<<<1, 256, 0, stream>>>(W4_w, W4_b, W5_w, W5_b, W6_w, W6_b,
                                    W_so_w, W_so_b, W_so2_w, W_so2_b, wts);
  k_nodes<<<NODE_BLOCKS, 256, 0, stream>>>(x_u, user_int, a_u, t, x_i, item_int, a_i,
                                           W_att_w, wts, u_rate, u_trust, i_rate,
                                           (uint2*)histP);
  k_edges<<<2048, 256, 0, stream>>>(rated_src, rated_dst, boun3, u_rate, i_rate,
                                    tp_src, tp_dst, tn_src, tn_dst, u_trust,
                                    wts, W_att_b, out, histP, histN, partR, partT);
  k_chunksum<<<1024, 256, 0, stream>>>((const uint4*)histP, (const uint4*)histN, chP, chN);
  k_aucap<<<NCH, 256, 0, stream>>>(histP, histN, chP, chN, partC, partA);
  k_final<<<1, 256, 0, stream>>>(partR, partT, partC, partA, out);
}